// Round 12
// baseline (1783.827 us; speedup 1.0000x reference)
//
#include <hip/hip_runtime.h>
#include <hip/hip_bf16.h>
#include <stdint.h>
#include <stdio.h>

// Problem geometry (fixed by the reference)
#define M_DIM 8192    // 4*2048
#define K_DIM 4096    // IN_FEATURES
#define N_DIM 11008   // OUT_FEATURES

#define BM 256
#define BN 256
#define BK 64
#define NT (K_DIM / BK)           // 64 K-tiles
#define TILES_M (M_DIM / BM)      // 32
#define TILES_N (N_DIM / BN)      // 43
#define NWG (TILES_M * TILES_N)   // 1376

typedef __bf16 bf16x8 __attribute__((ext_vector_type(8)));
typedef float f32x4 __attribute__((ext_vector_type(4)));

__device__ __constant__ float kFp4Code[16] = {
    0.0f,           0.0052083333f,  0.6666666666f, 1.0f,
    0.3333333333f,  0.5f,           0.1666666666f, 0.25f,
    -0.0f,          -0.0052083333f, -0.6666666666f, -1.0f,
    -0.3333333333f, -0.5f,          -0.1666666666f, -0.25f
};

// ---------------------------------------------------------------------------
// Kernel 1: FP4 dequant -> bf16 W [N_DIM][K_DIM]
// ---------------------------------------------------------------------------
__global__ __launch_bounds__(256) void fp4_dequant_kernel(
    const int* __restrict__ codes, const float* __restrict__ absmax,
    __hip_bfloat16* __restrict__ w)
{
    __shared__ float lut[16];
    if (threadIdx.x < 16) lut[threadIdx.x] = kFp4Code[threadIdx.x];
    __syncthreads();

    const int t = blockIdx.x * 256 + threadIdx.x;  // < 5,636,096
    const int4* cp = (const int4*)codes;
    const int4 c0 = cp[2 * t];
    const int4 c1 = cp[2 * t + 1];
    const float am = absmax[t >> 3];

    union { int4 v; __hip_bfloat16 h[8]; } u;
    u.h[0] = __float2bfloat16(lut[c0.x & 15] * am);
    u.h[1] = __float2bfloat16(lut[c0.y & 15] * am);
    u.h[2] = __float2bfloat16(lut[c0.z & 15] * am);
    u.h[3] = __float2bfloat16(lut[c0.w & 15] * am);
    u.h[4] = __float2bfloat16(lut[c1.x & 15] * am);
    u.h[5] = __float2bfloat16(lut[c1.y & 15] * am);
    u.h[6] = __float2bfloat16(lut[c1.z & 15] * am);
    u.h[7] = __float2bfloat16(lut[c1.w & 15] * am);
    ((int4*)w)[t] = u.v;
}

// ---------------------------------------------------------------------------
// Kernel 2: x fp32 -> bf16  [M_DIM][K_DIM]
// ---------------------------------------------------------------------------
__global__ __launch_bounds__(256) void f32_to_bf16_kernel(
    const float* __restrict__ x, __hip_bfloat16* __restrict__ y)
{
    const int t = blockIdx.x * 256 + threadIdx.x;  // < 4,194,304
    const float4* xp = (const float4*)x;
    const float4 a = xp[2 * t];
    const float4 b = xp[2 * t + 1];
    union { int4 v; __hip_bfloat16 h[8]; } u;
    u.h[0] = __float2bfloat16(a.x);
    u.h[1] = __float2bfloat16(a.y);
    u.h[2] = __float2bfloat16(a.z);
    u.h[3] = __float2bfloat16(a.w);
    u.h[4] = __float2bfloat16(b.x);
    u.h[5] = __float2bfloat16(b.y);
    u.h[6] = __float2bfloat16(b.z);
    u.h[7] = __float2bfloat16(b.w);
    ((int4*)y)[t] = u.v;
}

// ---------------------------------------------------------------------------
// Kernel 3: bf16 GEMM, C = A * B^T + bias  (256x256 tile, A-DIRECT variant)
//
// Round-12 change vs round-11: A FRAGMENTS LOADED DIRECTLY FROM GLOBAL (L2);
// only B staged through LDS. Evidence: rounds 5-11 — five scheduling attacks
// all failed to overlap the LDS pipe (192 b128 reads + 64KB gload-writes
// ~2300 cyc/tile/CU) with MFMA (2483 cyc) -> tile pinned ~5000 cyc. Fix:
// remove 2/3 of LDS reads + half the stage writes. A-operand per-lane rows
// are L2-resident (brick order): each global b128 load gathers 16 rows x 64B
// (cache-line pairs fully used across ks=0/1). L2 cost ~128KB/tile/CU
// (~950 cyc) on the VMEM pipe, under the MFMA floor.
//
// Windows (2 per K-tile; 10 vmem ops each: 2 B-stage gload_lds + 8 A-loads):
//  W0(t): stage B-hi(t+1)->LB1; load avHi(t); read bvLo(t) pre-bar;
//         vmcnt(10); bar; [MFMA Q00; mid-read bvHi(t); MFMA Q01]; bar.
//  W1(t): stage B-lo(t+2)->LB;  load avLo(t+1);
//         vmcnt(10); bar; [MFMA Q11; MFMA Q10]; bar.
// vmcnt(10) per window => all ops issued >=1 window earlier complete.
// Read ledger: bvLo(t) staged W1(t-2), confirmed W1(t-1) vmcnt+bar ✓;
//  bvHi(t) staged W0(t-1), all-wave-confirmed at bar#1(W0(t)) -> mid-cluster
//  read + sched_barrier(0) ✓; avLo(t) loaded W1(t-1), own-wave, covered by
//  W0(t) vmcnt(10) ✓; avHi(t) loaded W0(t), covered by W1(t) vmcnt(10) ✓.
// Overwrite ledger: B-lo(t) last read pre-bar W0(t), overwrite W1(t) (2 bars
//  after) ✓; B-hi(t) last read mid-W0(t), overwrite W0(t+1) (2 bars) ✓.
// Loads pinned to their window by asm "memory" clobbers (FIFO order stable).
// 2D brick order (round-9). XOR involution swizzle for B (0 conflicts).
// LDS 64KB: 2 dbuf x { B-lo@0, B-hi@16K }.
// ---------------------------------------------------------------------------
#define STAGE(gbase, eoff, loff)                                              \
    __builtin_amdgcn_global_load_lds(                                         \
        (const __attribute__((address_space(1))) void*)((gbase) + (eoff)),    \
        (__attribute__((address_space(3))) void*)(lds + (loff)), 16, 0, 0)

// 16 MFMAs: one quadrant (4m x 2n x 2ks), ks-outer (dependence distance 8)
__device__ __forceinline__ void mfma_half(
    f32x4 (&accq)[4][2], bf16x8 (&av)[4][2], bf16x8 (&bv)[2][2])
{
#pragma unroll
    for (int ks = 0; ks < 2; ++ks)
#pragma unroll
        for (int m = 0; m < 4; ++m)
#pragma unroll
            for (int n = 0; n < 2; ++n)
                accq[m][n] = __builtin_amdgcn_mfma_f32_16x16x32_bf16(
                    av[m][ks], bv[n][ks], accq[m][n], 0, 0, 0);
}

template<int BUF>
__device__ __forceinline__ void tile_body(
    int t, f32x4 (&acc)[4][4][2],
    const __hip_bfloat16* __restrict__ Abase,   // A + m0*K_DIM
    const __hip_bfloat16* __restrict__ B,
    char* lds,
    const int (&sB_lo)[2], const int (&sB_hi)[2],
    int dst0, int dst1, int aOff,
    const char* pB0, const char* pB1,
    bf16x8 (&avLo)[4][2], bf16x8 (&avHi)[4][2],
    bf16x8 (&bvLo)[2][2], bf16x8 (&bvHi)[2][2])
{
    constexpr int LB  = BUF * 32768;         // this tile's B buffer
    constexpr int LB1 = (BUF ^ 1) * 32768;   // (t+1)'s B buffer
    const int koff1 = ((t + 1) & (NT - 1)) * 64;
    const int koff2 = ((t + 2) & (NT - 1)) * 64;
    const __hip_bfloat16* At  = Abase + t * 64;   // uniform per window
    const __hip_bfloat16* At1 = Abase + koff1;

    // ================= W0 =================
    STAGE(B, sB_hi[0] + koff1, LB1 + 16384 + dst0);
    STAGE(B, sB_hi[1] + koff1, LB1 + 16384 + dst1);
#pragma unroll
    for (int m = 0; m < 4; ++m)
#pragma unroll
        for (int ks = 0; ks < 2; ++ks)
            avHi[m][ks] = *(const bf16x8*)(At + aOff + (128 + m * 16) * K_DIM + ks * 32);
    // pre-bar LDS reads: bvLo(t) (confirmed at W1(t-1) vmcnt+bar)
#pragma unroll
    for (int n = 0; n < 2; ++n) {
        bvLo[n][0] = *(const bf16x8*)(pB0 + LB + n * 2048);
        bvLo[n][1] = *(const bf16x8*)(pB1 + LB + n * 2048);
    }
    asm volatile("s_waitcnt vmcnt(10)" ::: "memory");
    __builtin_amdgcn_s_barrier();
    __builtin_amdgcn_sched_barrier(0);
    __builtin_amdgcn_s_setprio(1);
    mfma_half(acc[0], avLo, bvLo);         // Q(0,0)
    // mid-cluster: bvHi(t) all-wave-safe only after bar#1(W0(t))
#pragma unroll
    for (int n = 0; n < 2; ++n) {
        bvHi[n][0] = *(const bf16x8*)(pB0 + LB + 16384 + n * 2048);
        bvHi[n][1] = *(const bf16x8*)(pB1 + LB + 16384 + n * 2048);
    }
    mfma_half(acc[1], avLo, bvHi);         // Q(0,1)
    __builtin_amdgcn_s_setprio(0);
    __builtin_amdgcn_s_barrier();

    // ================= W1 =================
    STAGE(B, sB_lo[0] + koff2, LB + dst0);
    STAGE(B, sB_lo[1] + koff2, LB + dst1);
#pragma unroll
    for (int m = 0; m < 4; ++m)
#pragma unroll
        for (int ks = 0; ks < 2; ++ks)
            avLo[m][ks] = *(const bf16x8*)(At1 + aOff + (m * 16) * K_DIM + ks * 32);
    asm volatile("s_waitcnt vmcnt(10)" ::: "memory");
    __builtin_amdgcn_s_barrier();
    __builtin_amdgcn_sched_barrier(0);
    __builtin_amdgcn_s_setprio(1);
    mfma_half(acc[2], avHi, bvHi);         // Q(1,1)
    mfma_half(acc[3], avHi, bvLo);         // Q(1,0)
    __builtin_amdgcn_s_setprio(0);
    __builtin_amdgcn_s_barrier();
}

__global__ __launch_bounds__(512, 2) void gemm_bf16_adirect(
    const __hip_bfloat16* __restrict__ A, const __hip_bfloat16* __restrict__ B,
    const float* __restrict__ bias, float* __restrict__ C)
{
    extern __shared__ char lds[];  // 65536 B (B operand only)

    const int tid = threadIdx.x;
    const int lane = tid & 63;
    const int wid = tid >> 6;       // 0..7
    const int wr = wid >> 2;        // 0..1 (M split)
    const int wc = wid & 3;         // 0..3 (N split)
    const int l15 = lane & 15;
    const int kgrp = lane >> 4;

    // XCD stripe (bijective) + 2D brick order (round-9): per-XCD 8x4 bricks.
    const int wg = blockIdx.x;
    const int s = (wg & 7) * (NWG / 8) + (wg >> 3);
    int bm, bn;
    if (s < 1280) {                 // 10 groups of width 4 (8x4 bricks)
        const int g = s >> 7;
        const int j = s & 127;
        bm = j >> 2;
        bn = g * 4 + (j & 3);
    } else {                        // last group: width 3
        const int j = s - 1280;     // 0..95
        bm = j / 3;
        bn = 40 + j % 3;
    }
    const int m0 = bm * BM;
    const int n0 = bn * BN;
    const __hip_bfloat16* Abase = A + (size_t)m0 * K_DIM;

    // ---- B stage-source element offsets (per lane, once) ----
    int sB_lo[2], sB_hi[2];
#pragma unroll
    for (int c = 0; c < 2; ++c) {
        const int idx = c * 512 + tid;          // 0..1023 chunk id (linear LDS)
        const int row = idx >> 3;               // 0..127
        const int scol = (idx & 7) ^ (row & 7); // pre-swizzled source chunk
        sB_lo[c] = (n0 + row) * K_DIM + scol * 8;
        sB_hi[c] = sB_lo[c] + 128 * K_DIM;
    }
    const int dst0 = wid * 1024;          // (c*512 + wid*64)*16, c=0
    const int dst1 = 8192 + wid * 1024;   // c=1

    // ---- A per-lane fragment offset (element units) ----
    const int aOff = (wr * 64 + l15) * K_DIM + kgrp * 8;

    // ---- B fragment-read base pointers (buf0; buf1 = +32768) ----
    const int xlo = l15 & 7;
    const char* pB0 = lds + (wc * 32 + l15) * 128 + ((kgrp) ^ xlo) * 16;
    const char* pB1 = lds + (wc * 32 + l15) * 128 + ((4 + kgrp) ^ xlo) * 16;

    // acc quadrants: 0=(0,0) 1=(0,1) 2=(1,1) 3=(1,0)  (mq,nq)
    f32x4 acc[4][4][2];
#pragma unroll
    for (int q = 0; q < 4; ++q)
#pragma unroll
        for (int m = 0; m < 4; ++m)
#pragma unroll
            for (int n = 0; n < 2; ++n)
                acc[q][m][n] = (f32x4){0.f, 0.f, 0.f, 0.f};

    // Fragment registers (live across tile_body calls)
    bf16x8 avLo[4][2], avHi[4][2], bvLo[2][2], bvHi[2][2];

    // Prologue: B-lo(0), B-hi(0) -> buf0; B-lo(1) -> buf1; avLo(0) loads.
    STAGE(B, sB_lo[0], dst0);               STAGE(B, sB_lo[1], dst1);
    STAGE(B, sB_hi[0], 16384 + dst0);       STAGE(B, sB_hi[1], 16384 + dst1);
    STAGE(B, sB_lo[0] + 64, 32768 + dst0);  STAGE(B, sB_lo[1] + 64, 32768 + dst1);
#pragma unroll
    for (int m = 0; m < 4; ++m)
#pragma unroll
        for (int ks = 0; ks < 2; ++ks)
            avLo[m][ks] = *(const bf16x8*)(Abase + aOff + (m * 16) * K_DIM + ks * 32);
    asm volatile("s_waitcnt vmcnt(10)" ::: "memory"); // B-lo(0),B-hi(0) landed
    __builtin_amdgcn_s_barrier();

    for (int t = 0; t < NT; t += 2) {
        tile_body<0>(t,     acc, Abase, B, lds, sB_lo, sB_hi,
                     dst0, dst1, aOff, pB0, pB1, avLo, avHi, bvLo, bvHi);
        tile_body<1>(t + 1, acc, Abase, B, lds, sB_lo, sB_hi,
                     dst0, dst1, aOff, pB0, pB1, avLo, avHi, bvLo, bvHi);
    }

    // Epilogue (C/D layout: col = lane&15, row = (lane>>4)*4 + reg).
    // Nontemporal: C written once, never re-read -> don't churn L3.
#pragma unroll
    for (int q = 0; q < 4; ++q) {
        const int mqe = q >> 1;
        const int nqe = (q == 1 || q == 2) ? 1 : 0;
#pragma unroll
        for (int n = 0; n < 2; ++n) {
            const int col = n0 + nqe * 128 + wc * 32 + n * 16 + l15;
            const float bval = bias[col];
#pragma unroll
            for (int m = 0; m < 4; ++m) {
                const int row = m0 + mqe * 128 + wr * 64 + m * 16 + kgrp * 4;
#pragma unroll
                for (int r = 0; r < 4; ++r)
                    __builtin_nontemporal_store(acc[q][m][n][r] + bval,
                        &C[(size_t)(row + r) * N_DIM + col]);
            }
        }
    }
}

// ---------------------------------------------------------------------------
extern "C" void kernel_launch(void* const* d_in, const int* in_sizes, int n_in,
                              void* d_out, int out_size, void* d_ws, size_t ws_size,
                              hipStream_t stream)
{
    const float* x      = (const float*)d_in[0];  // [4,2048,4096] f32
    const int*   codes  = (const int*)d_in[1];    // [704512,64] i32
    const float* absmax = (const float*)d_in[2];  // [704512] f32
    const float* bias   = (const float*)d_in[3];  // [11008] f32
    float* out = (float*)d_out;                   // [4,2048,11008] f32

    const size_t w_bytes = (size_t)N_DIM * K_DIM * sizeof(__hip_bfloat16);
    const size_t x_bytes = (size_t)M_DIM * K_DIM * sizeof(__hip_bfloat16);
    if (ws_size < w_bytes + x_bytes) {
        fprintf(stderr, "kernel_launch: ws_size=%zu < needed %zu\n",
                ws_size, w_bytes + x_bytes);
        return;
    }
    __hip_bfloat16* wbf = (__hip_bfloat16*)d_ws;
    __hip_bfloat16* xbf = (__hip_bfloat16*)((char*)d_ws + w_bytes);

    hipFuncSetAttribute((const void*)gemm_bf16_adirect,
                        hipFuncAttributeMaxDynamicSharedMemorySize, 65536);

    fp4_dequant_kernel<<<dim3(22016), dim3(256), 0, stream>>>(codes, absmax, wbf);
    f32_to_bf16_kernel<<<dim3(16384), dim3(256), 0, stream>>>(x, xbf);
    gemm_bf16_adirect<<<dim3(NWG), dim3(512), 65536, stream>>>(xbf, wbf, bias, out);
}

// Round 13
// 1779.565 us; speedup vs baseline: 1.0024x; 1.0024x over previous
//
#include <hip/hip_runtime.h>
#include <hip/hip_bf16.h>
#include <stdint.h>
#include <stdio.h>

// Problem geometry (fixed by the reference)
#define M_DIM 8192    // 4*2048
#define K_DIM 4096    // IN_FEATURES
#define N_DIM 11008   // OUT_FEATURES

#define BM 256
#define BN 256
#define BK 64
#define NT (K_DIM / BK)           // 64 K-tiles
#define TILES_M (M_DIM / BM)      // 32
#define TILES_N (N_DIM / BN)      // 43
#define NWG (TILES_M * TILES_N)   // 1376

typedef __bf16 bf16x8 __attribute__((ext_vector_type(8)));
typedef float f32x4 __attribute__((ext_vector_type(4)));

__device__ __constant__ float kFp4Code[16] = {
    0.0f,           0.0052083333f,  0.6666666666f, 1.0f,
    0.3333333333f,  0.5f,           0.1666666666f, 0.25f,
    -0.0f,          -0.0052083333f, -0.6666666666f, -1.0f,
    -0.3333333333f, -0.5f,          -0.1666666666f, -0.25f
};

// ---------------------------------------------------------------------------
// Kernel 1: FP4 dequant -> bf16 W [N_DIM][K_DIM]
// ---------------------------------------------------------------------------
__global__ __launch_bounds__(256) void fp4_dequant_kernel(
    const int* __restrict__ codes, const float* __restrict__ absmax,
    __hip_bfloat16* __restrict__ w)
{
    __shared__ float lut[16];
    if (threadIdx.x < 16) lut[threadIdx.x] = kFp4Code[threadIdx.x];
    __syncthreads();

    const int t = blockIdx.x * 256 + threadIdx.x;  // < 5,636,096
    const int4* cp = (const int4*)codes;
    const int4 c0 = cp[2 * t];
    const int4 c1 = cp[2 * t + 1];
    const float am = absmax[t >> 3];

    union { int4 v; __hip_bfloat16 h[8]; } u;
    u.h[0] = __float2bfloat16(lut[c0.x & 15] * am);
    u.h[1] = __float2bfloat16(lut[c0.y & 15] * am);
    u.h[2] = __float2bfloat16(lut[c0.z & 15] * am);
    u.h[3] = __float2bfloat16(lut[c0.w & 15] * am);
    u.h[4] = __float2bfloat16(lut[c1.x & 15] * am);
    u.h[5] = __float2bfloat16(lut[c1.y & 15] * am);
    u.h[6] = __float2bfloat16(lut[c1.z & 15] * am);
    u.h[7] = __float2bfloat16(lut[c1.w & 15] * am);
    ((int4*)w)[t] = u.v;
}

// ---------------------------------------------------------------------------
// Kernel 2: x fp32 -> bf16  [M_DIM][K_DIM]
// ---------------------------------------------------------------------------
__global__ __launch_bounds__(256) void f32_to_bf16_kernel(
    const float* __restrict__ x, __hip_bfloat16* __restrict__ y)
{
    const int t = blockIdx.x * 256 + threadIdx.x;  // < 4,194,304
    const float4* xp = (const float4*)x;
    const float4 a = xp[2 * t];
    const float4 b = xp[2 * t + 1];
    union { int4 v; __hip_bfloat16 h[8]; } u;
    u.h[0] = __float2bfloat16(a.x);
    u.h[1] = __float2bfloat16(a.y);
    u.h[2] = __float2bfloat16(a.z);
    u.h[3] = __float2bfloat16(a.w);
    u.h[4] = __float2bfloat16(b.x);
    u.h[5] = __float2bfloat16(b.y);
    u.h[6] = __float2bfloat16(b.z);
    u.h[7] = __float2bfloat16(b.w);
    ((int4*)y)[t] = u.v;
}

// ---------------------------------------------------------------------------
// Kernel 3: bf16 GEMM, C = A * B^T + bias  (256x256 tile, A-DIRECT variant)
//
// Round-12 change vs round-11: A FRAGMENTS LOADED DIRECTLY FROM GLOBAL (L2);
// only B staged through LDS. Evidence: rounds 5-11 — five scheduling attacks
// all failed to overlap the LDS pipe (192 b128 reads + 64KB gload-writes
// ~2300 cyc/tile/CU) with MFMA (2483 cyc) -> tile pinned ~5000 cyc. Fix:
// remove 2/3 of LDS reads + half the stage writes. A-operand per-lane rows
// are L2-resident (brick order): each global b128 load gathers 16 rows x 64B
// (cache-line pairs fully used across ks=0/1). L2 cost ~128KB/tile/CU
// (~950 cyc) on the VMEM pipe, under the MFMA floor.
//
// Windows (2 per K-tile; 10 vmem ops each: 2 B-stage gload_lds + 8 A-loads):
//  W0(t): stage B-hi(t+1)->LB1; load avHi(t); read bvLo(t) pre-bar;
//         vmcnt(10); bar; [MFMA Q00; mid-read bvHi(t); MFMA Q01]; bar.
//  W1(t): stage B-lo(t+2)->LB;  load avLo(t+1);
//         vmcnt(10); bar; [MFMA Q11; MFMA Q10]; bar.
// vmcnt(10) per window => all ops issued >=1 window earlier complete.
// Read ledger: bvLo(t) staged W1(t-2), confirmed W1(t-1) vmcnt+bar ✓;
//  bvHi(t) staged W0(t-1), all-wave-confirmed at bar#1(W0(t)) -> mid-cluster
//  read + sched_barrier(0) ✓; avLo(t) loaded W1(t-1), own-wave, covered by
//  W0(t) vmcnt(10) ✓; avHi(t) loaded W0(t), covered by W1(t) vmcnt(10) ✓.
// Overwrite ledger: B-lo(t) last read pre-bar W0(t), overwrite W1(t) (2 bars
//  after) ✓; B-hi(t) last read mid-W0(t), overwrite W0(t+1) (2 bars) ✓.
// Loads pinned to their window by asm "memory" clobbers (FIFO order stable).
// 2D brick order (round-9). XOR involution swizzle for B (0 conflicts).
// LDS 64KB: 2 dbuf x { B-lo@0, B-hi@16K }.
// ---------------------------------------------------------------------------
#define STAGE(gbase, eoff, loff)                                              \
    __builtin_amdgcn_global_load_lds(                                         \
        (const __attribute__((address_space(1))) void*)((gbase) + (eoff)),    \
        (__attribute__((address_space(3))) void*)(lds + (loff)), 16, 0, 0)

// 16 MFMAs: one quadrant (4m x 2n x 2ks), ks-outer (dependence distance 8)
__device__ __forceinline__ void mfma_half(
    f32x4 (&accq)[4][2], bf16x8 (&av)[4][2], bf16x8 (&bv)[2][2])
{
#pragma unroll
    for (int ks = 0; ks < 2; ++ks)
#pragma unroll
        for (int m = 0; m < 4; ++m)
#pragma unroll
            for (int n = 0; n < 2; ++n)
                accq[m][n] = __builtin_amdgcn_mfma_f32_16x16x32_bf16(
                    av[m][ks], bv[n][ks], accq[m][n], 0, 0, 0);
}

template<int BUF>
__device__ __forceinline__ void tile_body(
    int t, f32x4 (&acc)[4][4][2],
    const __hip_bfloat16* __restrict__ Abase,   // A + m0*K_DIM
    const __hip_bfloat16* __restrict__ B,
    char* lds,
    const int (&sB_lo)[2], const int (&sB_hi)[2],
    int dst0, int dst1, int aOff,
    const char* pB0, const char* pB1,
    bf16x8 (&avLo)[4][2], bf16x8 (&avHi)[4][2],
    bf16x8 (&bvLo)[2][2], bf16x8 (&bvHi)[2][2])
{
    constexpr int LB  = BUF * 32768;         // this tile's B buffer
    constexpr int LB1 = (BUF ^ 1) * 32768;   // (t+1)'s B buffer
    const int koff1 = ((t + 1) & (NT - 1)) * 64;
    const int koff2 = ((t + 2) & (NT - 1)) * 64;
    const __hip_bfloat16* At  = Abase + t * 64;   // uniform per window
    const __hip_bfloat16* At1 = Abase + koff1;

    // ================= W0 =================
    STAGE(B, sB_hi[0] + koff1, LB1 + 16384 + dst0);
    STAGE(B, sB_hi[1] + koff1, LB1 + 16384 + dst1);
#pragma unroll
    for (int m = 0; m < 4; ++m)
#pragma unroll
        for (int ks = 0; ks < 2; ++ks)
            avHi[m][ks] = *(const bf16x8*)(At + aOff + (128 + m * 16) * K_DIM + ks * 32);
    // pre-bar LDS reads: bvLo(t) (confirmed at W1(t-1) vmcnt+bar)
#pragma unroll
    for (int n = 0; n < 2; ++n) {
        bvLo[n][0] = *(const bf16x8*)(pB0 + LB + n * 2048);
        bvLo[n][1] = *(const bf16x8*)(pB1 + LB + n * 2048);
    }
    asm volatile("s_waitcnt vmcnt(10)" ::: "memory");
    __builtin_amdgcn_s_barrier();
    __builtin_amdgcn_sched_barrier(0);
    __builtin_amdgcn_s_setprio(1);
    mfma_half(acc[0], avLo, bvLo);         // Q(0,0)
    // mid-cluster: bvHi(t) all-wave-safe only after bar#1(W0(t))
#pragma unroll
    for (int n = 0; n < 2; ++n) {
        bvHi[n][0] = *(const bf16x8*)(pB0 + LB + 16384 + n * 2048);
        bvHi[n][1] = *(const bf16x8*)(pB1 + LB + 16384 + n * 2048);
    }
    mfma_half(acc[1], avLo, bvHi);         // Q(0,1)
    __builtin_amdgcn_s_setprio(0);
    __builtin_amdgcn_s_barrier();

    // ================= W1 =================
    STAGE(B, sB_lo[0] + koff2, LB + dst0);
    STAGE(B, sB_lo[1] + koff2, LB + dst1);
#pragma unroll
    for (int m = 0; m < 4; ++m)
#pragma unroll
        for (int ks = 0; ks < 2; ++ks)
            avLo[m][ks] = *(const bf16x8*)(At1 + aOff + (m * 16) * K_DIM + ks * 32);
    asm volatile("s_waitcnt vmcnt(10)" ::: "memory");
    __builtin_amdgcn_s_barrier();
    __builtin_amdgcn_sched_barrier(0);
    __builtin_amdgcn_s_setprio(1);
    mfma_half(acc[2], avHi, bvHi);         // Q(1,1)
    mfma_half(acc[3], avHi, bvLo);         // Q(1,0)
    __builtin_amdgcn_s_setprio(0);
    __builtin_amdgcn_s_barrier();
}

__global__ __launch_bounds__(512, 2) void gemm_bf16_adirect(
    const __hip_bfloat16* __restrict__ A, const __hip_bfloat16* __restrict__ B,
    const float* __restrict__ bias, float* __restrict__ C)
{
    extern __shared__ char lds[];  // 65536 B (B operand only)

    const int tid = threadIdx.x;
    const int lane = tid & 63;
    const int wid = tid >> 6;       // 0..7
    const int wr = wid >> 2;        // 0..1 (M split)
    const int wc = wid & 3;         // 0..3 (N split)
    const int l15 = lane & 15;
    const int kgrp = lane >> 4;

    // XCD stripe (bijective) + 2D brick order (round-9): per-XCD 8x4 bricks.
    const int wg = blockIdx.x;
    const int s = (wg & 7) * (NWG / 8) + (wg >> 3);
    int bm, bn;
    if (s < 1280) {                 // 10 groups of width 4 (8x4 bricks)
        const int g = s >> 7;
        const int j = s & 127;
        bm = j >> 2;
        bn = g * 4 + (j & 3);
    } else {                        // last group: width 3
        const int j = s - 1280;     // 0..95
        bm = j / 3;
        bn = 40 + j % 3;
    }
    const int m0 = bm * BM;
    const int n0 = bn * BN;
    const __hip_bfloat16* Abase = A + (size_t)m0 * K_DIM;

    // ---- B stage-source element offsets (per lane, once) ----
    int sB_lo[2], sB_hi[2];
#pragma unroll
    for (int c = 0; c < 2; ++c) {
        const int idx = c * 512 + tid;          // 0..1023 chunk id (linear LDS)
        const int row = idx >> 3;               // 0..127
        const int scol = (idx & 7) ^ (row & 7); // pre-swizzled source chunk
        sB_lo[c] = (n0 + row) * K_DIM + scol * 8;
        sB_hi[c] = sB_lo[c] + 128 * K_DIM;
    }
    const int dst0 = wid * 1024;          // (c*512 + wid*64)*16, c=0
    const int dst1 = 8192 + wid * 1024;   // c=1

    // ---- A per-lane fragment offset (element units) ----
    const int aOff = (wr * 64 + l15) * K_DIM + kgrp * 8;

    // ---- B fragment-read base pointers (buf0; buf1 = +32768) ----
    const int xlo = l15 & 7;
    const char* pB0 = lds + (wc * 32 + l15) * 128 + ((kgrp) ^ xlo) * 16;
    const char* pB1 = lds + (wc * 32 + l15) * 128 + ((4 + kgrp) ^ xlo) * 16;

    // acc quadrants: 0=(0,0) 1=(0,1) 2=(1,1) 3=(1,0)  (mq,nq)
    f32x4 acc[4][4][2];
#pragma unroll
    for (int q = 0; q < 4; ++q)
#pragma unroll
        for (int m = 0; m < 4; ++m)
#pragma unroll
            for (int n = 0; n < 2; ++n)
                acc[q][m][n] = (f32x4){0.f, 0.f, 0.f, 0.f};

    // Fragment registers (live across tile_body calls)
    bf16x8 avLo[4][2], avHi[4][2], bvLo[2][2], bvHi[2][2];

    // Prologue: B-lo(0), B-hi(0) -> buf0; B-lo(1) -> buf1; avLo(0) loads.
    STAGE(B, sB_lo[0], dst0);               STAGE(B, sB_lo[1], dst1);
    STAGE(B, sB_hi[0], 16384 + dst0);       STAGE(B, sB_hi[1], 16384 + dst1);
    STAGE(B, sB_lo[0] + 64, 32768 + dst0);  STAGE(B, sB_lo[1] + 64, 32768 + dst1);
#pragma unroll
    for (int m = 0; m < 4; ++m)
#pragma unroll
        for (int ks = 0; ks < 2; ++ks)
            avLo[m][ks] = *(const bf16x8*)(Abase + aOff + (m * 16) * K_DIM + ks * 32);
    asm volatile("s_waitcnt vmcnt(10)" ::: "memory"); // B-lo(0),B-hi(0) landed
    __builtin_amdgcn_s_barrier();

    for (int t = 0; t < NT; t += 2) {
        tile_body<0>(t,     acc, Abase, B, lds, sB_lo, sB_hi,
                     dst0, dst1, aOff, pB0, pB1, avLo, avHi, bvLo, bvHi);
        tile_body<1>(t + 1, acc, Abase, B, lds, sB_lo, sB_hi,
                     dst0, dst1, aOff, pB0, pB1, avLo, avHi, bvLo, bvHi);
    }

    // Epilogue (C/D layout: col = lane&15, row = (lane>>4)*4 + reg).
    // Nontemporal: C written once, never re-read -> don't churn L3.
#pragma unroll
    for (int q = 0; q < 4; ++q) {
        const int mqe = q >> 1;
        const int nqe = (q == 1 || q == 2) ? 1 : 0;
#pragma unroll
        for (int n = 0; n < 2; ++n) {
            const int col = n0 + nqe * 128 + wc * 32 + n * 16 + l15;
            const float bval = bias[col];
#pragma unroll
            for (int m = 0; m < 4; ++m) {
                const int row = m0 + mqe * 128 + wr * 64 + m * 16 + kgrp * 4;
#pragma unroll
                for (int r = 0; r < 4; ++r)
                    __builtin_nontemporal_store(acc[q][m][n][r] + bval,
                        &C[(size_t)(row + r) * N_DIM + col]);
            }
        }
    }
}

// ---------------------------------------------------------------------------
extern "C" void kernel_launch(void* const* d_in, const int* in_sizes, int n_in,
                              void* d_out, int out_size, void* d_ws, size_t ws_size,
                              hipStream_t stream)
{
    const float* x      = (const float*)d_in[0];  // [4,2048,4096] f32
    const int*   codes  = (const int*)d_in[1];    // [704512,64] i32
    const float* absmax = (const float*)d_in[2];  // [704512] f32
    const float* bias   = (const float*)d_in[3];  // [11008] f32
    float* out = (float*)d_out;                   // [4,2048,11008] f32

    const size_t w_bytes = (size_t)N_DIM * K_DIM * sizeof(__hip_bfloat16);
    const size_t x_bytes = (size_t)M_DIM * K_DIM * sizeof(__hip_bfloat16);
    if (ws_size < w_bytes + x_bytes) {
        fprintf(stderr, "kernel_launch: ws_size=%zu < needed %zu\n",
                ws_size, w_bytes + x_bytes);
        return;
    }
    __hip_bfloat16* wbf = (__hip_bfloat16*)d_ws;
    __hip_bfloat16* xbf = (__hip_bfloat16*)((char*)d_ws + w_bytes);

    hipFuncSetAttribute((const void*)gemm_bf16_adirect,
                        hipFuncAttributeMaxDynamicSharedMemorySize, 65536);

    fp4_dequant_kernel<<<dim3(22016), dim3(256), 0, stream>>>(codes, absmax, wbf);
    f32_to_bf16_kernel<<<dim3(16384), dim3(256), 0, stream>>>(x, xbf);
    gemm_bf16_adirect<<<dim3(NWG), dim3(512), 65536, stream>>>(xbf, wbf, bias, out);
}

// Round 14
// 766.596 us; speedup vs baseline: 2.3269x; 2.3214x over previous
//
#include <hip/hip_runtime.h>
#include <hip/hip_bf16.h>
#include <stdint.h>
#include <stdio.h>

// Problem geometry (fixed by the reference)
#define M_DIM 8192    // 4*2048
#define K_DIM 4096    // IN_FEATURES
#define N_DIM 11008   // OUT_FEATURES

// 128x128 tile, 4 waves, 64KB LDS -> TWO blocks per CU (cross-block overlap)
#define BM 128
#define BN 128
#define BK 64
#define NT (K_DIM / BK)           // 64 K-tiles
#define TILES_M (M_DIM / BM)      // 64
#define TILES_N (N_DIM / BN)      // 86
#define NWG (TILES_M * TILES_N)   // 5504 (%8==0 -> XCD stripe bijective)

typedef __bf16 bf16x8 __attribute__((ext_vector_type(8)));
typedef float f32x4 __attribute__((ext_vector_type(4)));

__device__ __constant__ float kFp4Code[16] = {
    0.0f,           0.0052083333f,  0.6666666666f, 1.0f,
    0.3333333333f,  0.5f,           0.1666666666f, 0.25f,
    -0.0f,          -0.0052083333f, -0.6666666666f, -1.0f,
    -0.3333333333f, -0.5f,          -0.1666666666f, -0.25f
};

// ---------------------------------------------------------------------------
// Kernel 1: FP4 dequant -> bf16 W [N_DIM][K_DIM]
// ---------------------------------------------------------------------------
__global__ __launch_bounds__(256) void fp4_dequant_kernel(
    const int* __restrict__ codes, const float* __restrict__ absmax,
    __hip_bfloat16* __restrict__ w)
{
    __shared__ float lut[16];
    if (threadIdx.x < 16) lut[threadIdx.x] = kFp4Code[threadIdx.x];
    __syncthreads();

    const int t = blockIdx.x * 256 + threadIdx.x;  // < 5,636,096
    const int4* cp = (const int4*)codes;
    const int4 c0 = cp[2 * t];
    const int4 c1 = cp[2 * t + 1];
    const float am = absmax[t >> 3];

    union { int4 v; __hip_bfloat16 h[8]; } u;
    u.h[0] = __float2bfloat16(lut[c0.x & 15] * am);
    u.h[1] = __float2bfloat16(lut[c0.y & 15] * am);
    u.h[2] = __float2bfloat16(lut[c0.z & 15] * am);
    u.h[3] = __float2bfloat16(lut[c0.w & 15] * am);
    u.h[4] = __float2bfloat16(lut[c1.x & 15] * am);
    u.h[5] = __float2bfloat16(lut[c1.y & 15] * am);
    u.h[6] = __float2bfloat16(lut[c1.z & 15] * am);
    u.h[7] = __float2bfloat16(lut[c1.w & 15] * am);
    ((int4*)w)[t] = u.v;
}

// ---------------------------------------------------------------------------
// Kernel 2: x fp32 -> bf16  [M_DIM][K_DIM]
// ---------------------------------------------------------------------------
__global__ __launch_bounds__(256) void f32_to_bf16_kernel(
    const float* __restrict__ x, __hip_bfloat16* __restrict__ y)
{
    const int t = blockIdx.x * 256 + threadIdx.x;  // < 4,194,304
    const float4* xp = (const float4*)x;
    const float4 a = xp[2 * t];
    const float4 b = xp[2 * t + 1];
    union { int4 v; __hip_bfloat16 h[8]; } u;
    u.h[0] = __float2bfloat16(a.x);
    u.h[1] = __float2bfloat16(a.y);
    u.h[2] = __float2bfloat16(a.z);
    u.h[3] = __float2bfloat16(a.w);
    u.h[4] = __float2bfloat16(b.x);
    u.h[5] = __float2bfloat16(b.y);
    u.h[6] = __float2bfloat16(b.z);
    u.h[7] = __float2bfloat16(b.w);
    ((int4*)y)[t] = u.v;
}

// ---------------------------------------------------------------------------
// Kernel 3: bf16 GEMM, C = A * B^T + bias  (128x128 tile, 2 BLOCKS PER CU)
//
// Round-14 rationale: rounds 5-11 proved intra-block scheduling cannot
// overlap the LDS-read segment with the MFMA segment (all 8 waves lockstep
// on the same barriers); round-13's A-direct (VMEM gathers) was 2.5x worse.
// The one HW-verified overlap mechanism left is CROSS-BLOCK (m114: two
// co-resident blocks' pipes co-schedule, time ~ max not sum). 128KB LDS
// forced 1 block/CU; this kernel: 64KB LDS + 4-wave blocks -> 2 blocks/CU
// (independent barrier domains). Tail also improves: 5504 blocks/512 slots
// (2.3% quantization) vs 1376/256 (11.6%).
//
// Per K-tile window: stage next tile (8 gload_lds) -> vmcnt(8) -> bar ->
// 16 ds_read_b128 -> 32 MFMA (ks-outer) -> bar.
// vmcnt ledger (per-wave, 8 gloads/window): vmcnt(8) leaves only this
// window's 8 in flight -> confirms stage(t) (issued last window) before
// bar#1; all waves' reads after bar#1 are safe. Overwrite: buf b's last
// reads complete before MFMA(t) < bar#2(t); overwriting stage(t+2) issues
// in window t+1 after bar#2(t) -> >=1 barrier ✓.
// XOR involution swizzle (round-2-proven, 0 conflicts): LDS slot (row,c)
// holds global chunk (row, c^(row&7)); gload_lds dest LINEAR.
// LDS per buffer: A[128][64]@0 (16KB), B[128][64]@16384; buf stride 32768.
// 2D brick order: per-XCD 8(m)x8(n) bricks (~64 concurrent blocks/XCD).
// ---------------------------------------------------------------------------
#define STAGE(gbase, eoff, loff)                                              \
    __builtin_amdgcn_global_load_lds(                                         \
        (const __attribute__((address_space(1))) void*)((gbase) + (eoff)),    \
        (__attribute__((address_space(3))) void*)(lds + (loff)), 16, 0, 0)

template<int BUF>
__device__ __forceinline__ void tile_body(
    int t, f32x4 (&acc)[4][4],
    const __hip_bfloat16* __restrict__ A, const __hip_bfloat16* __restrict__ B,
    char* lds,
    const int (&sA)[4], const int (&sB)[4], int wid,
    const char* pA0, const char* pA1, const char* pB0, const char* pB1)
{
    constexpr int LB  = BUF * 32768;         // this tile's buffer
    constexpr int LB1 = (BUF ^ 1) * 32768;   // next tile's buffer
    const int koff = ((t + 1) & (NT - 1)) * 64;   // wave-uniform (SALU)

    // ---- stage tile t+1 into the other buffer (8 gloads/wave) ----
#pragma unroll
    for (int c = 0; c < 4; ++c)
        STAGE(A, sA[c] + koff, LB1 + c * 4096 + wid * 1024);
#pragma unroll
    for (int c = 0; c < 4; ++c)
        STAGE(B, sB[c] + koff, LB1 + 16384 + c * 4096 + wid * 1024);

    // confirm stage(t) (issued last window; only this window's 8 stay out)
    asm volatile("s_waitcnt vmcnt(8)" ::: "memory");
    __builtin_amdgcn_s_barrier();
    __builtin_amdgcn_sched_barrier(0);   // nothing hoists above the barrier

    // ---- read tile t fragments (16 ds_read_b128) ----
    bf16x8 av[4][2], bv[4][2];
#pragma unroll
    for (int m = 0; m < 4; ++m) {
        av[m][0] = *(const bf16x8*)(pA0 + LB + m * 2048);
        av[m][1] = *(const bf16x8*)(pA1 + LB + m * 2048);
    }
#pragma unroll
    for (int n = 0; n < 4; ++n) {
        bv[n][0] = *(const bf16x8*)(pB0 + LB + n * 2048);
        bv[n][1] = *(const bf16x8*)(pB1 + LB + n * 2048);
    }

    // ---- 32 MFMA, ks-outer (16 independent chains) ----
    __builtin_amdgcn_s_setprio(1);
#pragma unroll
    for (int ks = 0; ks < 2; ++ks)
#pragma unroll
        for (int m = 0; m < 4; ++m)
#pragma unroll
            for (int n = 0; n < 4; ++n)
                acc[m][n] = __builtin_amdgcn_mfma_f32_16x16x32_bf16(
                    av[m][ks], bv[n][ks], acc[m][n], 0, 0, 0);
    __builtin_amdgcn_s_setprio(0);
    __builtin_amdgcn_s_barrier();
}

__global__ __launch_bounds__(256, 2) void gemm_bf16_2blk(
    const __hip_bfloat16* __restrict__ A, const __hip_bfloat16* __restrict__ B,
    const float* __restrict__ bias, float* __restrict__ C)
{
    extern __shared__ char lds[];  // 65536 B

    const int tid = threadIdx.x;
    const int lane = tid & 63;
    const int wid = tid >> 6;       // 0..3
    const int wr = wid >> 1;        // 0..1 (M split)
    const int wc = wid & 1;         // 0..1 (N split)
    const int l15 = lane & 15;
    const int kgrp = lane >> 4;

    // XCD stripe (bijective, NWG%8==0) + 2D brick order: each XCD's ~64
    // concurrent blocks form 8(m) x 8(n) -> A shared 8-way, B 8-way in L2.
    const int wg = blockIdx.x;
    const int s = (wg & 7) * (NWG / 8) + (wg >> 3);
    int bm, bn;
    if (s < 5120) {                 // 10 groups of width 8 (64x8 each)
        const int g = s >> 9;
        const int j = s & 511;
        bm = j >> 3;
        bn = g * 8 + (j & 7);
    } else {                        // last group: width 6
        const int j = s - 5120;     // 0..383
        bm = j / 6;
        bn = 80 + j % 6;
    }
    const int m0 = bm * BM;
    const int n0 = bn * BN;

    // ---- Stage-source element offsets (per lane, once). Tile = 16KB =
    //      1024 chunks of 16B; 256 thr x 4 chunks; linear LDS dest. ----
    int sA[4], sB[4];
#pragma unroll
    for (int c = 0; c < 4; ++c) {
        const int idx = c * 256 + tid;          // 0..1023 chunk id
        const int row = idx >> 3;               // 0..127
        const int scol = (idx & 7) ^ (row & 7); // pre-swizzled source chunk
        sA[c] = (m0 + row) * K_DIM + scol * 8;
        sB[c] = (n0 + row) * K_DIM + scol * 8;
    }

    // ---- Fragment-read base pointers (buf0; buf1 = +32768) ----
    const int xlo = l15 & 7;
    const char* pA0 = lds + (wr * 64 + l15) * 128 + ((kgrp) ^ xlo) * 16;
    const char* pA1 = lds + (wr * 64 + l15) * 128 + ((4 + kgrp) ^ xlo) * 16;
    const char* pB0 = lds + 16384 + (wc * 64 + l15) * 128 + ((kgrp) ^ xlo) * 16;
    const char* pB1 = lds + 16384 + (wc * 64 + l15) * 128 + ((4 + kgrp) ^ xlo) * 16;

    f32x4 acc[4][4];
#pragma unroll
    for (int m = 0; m < 4; ++m)
#pragma unroll
        for (int n = 0; n < 4; ++n)
            acc[m][n] = (f32x4){0.f, 0.f, 0.f, 0.f};

    // Prologue: stage tile0 -> buf0 only. Window 0 stages tile1, then its
    // vmcnt(8) drains tile0 (16 outstanding -> 8) before bar#1 + reads.
#pragma unroll
    for (int c = 0; c < 4; ++c)
        STAGE(A, sA[c], c * 4096 + wid * 1024);
#pragma unroll
    for (int c = 0; c < 4; ++c)
        STAGE(B, sB[c], 16384 + c * 4096 + wid * 1024);

    for (int t = 0; t < NT; t += 2) {
        tile_body<0>(t,     acc, A, B, lds, sA, sB, wid, pA0, pA1, pB0, pB1);
        tile_body<1>(t + 1, acc, A, B, lds, sA, sB, wid, pA0, pA1, pB0, pB1);
    }

    // Epilogue (C/D layout: col = lane&15, row = (lane>>4)*4 + reg).
    // Nontemporal: C written once, never re-read -> don't churn L3.
#pragma unroll
    for (int n = 0; n < 4; ++n) {
        const int col = n0 + wc * 64 + n * 16 + l15;
        const float bval = bias[col];
#pragma unroll
        for (int m = 0; m < 4; ++m) {
            const int rowb = m0 + wr * 64 + m * 16 + kgrp * 4;
#pragma unroll
            for (int r = 0; r < 4; ++r)
                __builtin_nontemporal_store(acc[m][n][r] + bval,
                    &C[(size_t)(rowb + r) * N_DIM + col]);
        }
    }
}

// ---------------------------------------------------------------------------
extern "C" void kernel_launch(void* const* d_in, const int* in_sizes, int n_in,
                              void* d_out, int out_size, void* d_ws, size_t ws_size,
                              hipStream_t stream)
{
    const float* x      = (const float*)d_in[0];  // [4,2048,4096] f32
    const int*   codes  = (const int*)d_in[1];    // [704512,64] i32
    const float* absmax = (const float*)d_in[2];  // [704512] f32
    const float* bias   = (const float*)d_in[3];  // [11008] f32
    float* out = (float*)d_out;                   // [4,2048,11008] f32

    const size_t w_bytes = (size_t)N_DIM * K_DIM * sizeof(__hip_bfloat16);
    const size_t x_bytes = (size_t)M_DIM * K_DIM * sizeof(__hip_bfloat16);
    if (ws_size < w_bytes + x_bytes) {
        fprintf(stderr, "kernel_launch: ws_size=%zu < needed %zu\n",
                ws_size, w_bytes + x_bytes);
        return;
    }
    __hip_bfloat16* wbf = (__hip_bfloat16*)d_ws;
    __hip_bfloat16* xbf = (__hip_bfloat16*)((char*)d_ws + w_bytes);

    hipFuncSetAttribute((const void*)gemm_bf16_2blk,
                        hipFuncAttributeMaxDynamicSharedMemorySize, 65536);

    fp4_dequant_kernel<<<dim3(22016), dim3(256), 0, stream>>>(codes, absmax, wbf);
    f32_to_bf16_kernel<<<dim3(16384), dim3(256), 0, stream>>>(x, xbf);
    gemm_bf16_2blk<<<dim3(NWG), dim3(256), 65536, stream>>>(xbf, wbf, bias, out);
}